// Round 24
// baseline (122.183 us; speedup 1.0000x reference)
//
#include <hip/hip_runtime.h>
#include <hip/hip_bf16.h>

typedef __hip_bfloat16 bf16;
typedef __attribute__((ext_vector_type(8))) short bf16x8;
typedef __attribute__((ext_vector_type(4))) float f32x4;

// Problem constants: B=4, H=W=60, C=256, HEADS=8, hd=32, WS=7 -> 9x9 windows/batch,
// 324 windows, 49 q/window, key window 27x27=729 gathered from the 27x27 stride-3
// grid. KEY IDENTITY: token = kk + C with C = 81*wh + 3*ww - 336 -> contiguous
// token slice; invalid keys killed by precomputed ADDITIVE mask (-30000).
// All external I/O f32; staging bf16 (attn) / fp8-e4m3 (MLP). Softmax in log2
// domain (q pre-scaled by hd^-0.5*log2(e); exp = v_exp_f32).
//
// Verified MFMA lane mapping (16x16x32, rounds 3-23):
//   A-frag: lane(li=lane&15, lg=lane>>4) holds A[row=li][k=lg*8+e (mod 32)]
//   B-frag: lane holds B[col=li][k=lg*8+e]
//   C/D   : [row=lg*4+r][col=li]   (dtype-independent on gfx950)
// fp8 note: A and B are packed with the SAME assumed (lg,e)->k byte order, so
// any HW k-permutation cancels in the contraction.
// Round 24: projmlp fc1/fc2 weight streams get 2-DEEP register pipelines
// (mod-3 buffers, fully unrolled -> static indices) to cover ~200cy L2 load
// latency (1-deep covers ~1/3 of it); s_setprio(1) around MFMA clusters (T5;
// 8-wave phase-split structure = the measured precondition).

#define QSCALE 0.25505402616302864f  // (1/sqrt(32)) * log2(e)

__device__ __forceinline__ bf16 f2bf(float f){ return __float2bfloat16(f); }
__device__ __forceinline__ unsigned short f2bfu(float f){
  __hip_bfloat16 h = __float2bfloat16(f);
  return *(unsigned short*)&h;
}
__device__ __forceinline__ float fexp2(float x){
  float r; asm("v_exp_f32 %0, %1" : "=v"(r) : "v"(x)); return r;
}
__device__ __forceinline__ unsigned cvtpk(float lo, float hi){
  unsigned r; asm("v_cvt_pk_bf16_f32 %0, %1, %2" : "=v"(r) : "v"(lo), "v"(hi));
  return r;
}
// f32 -> fp8 e4m3 (OCP on gfx950). pk writes 2 bytes; lo = bits 15:0, hi = 31:16.
__device__ __forceinline__ unsigned pk8lo(float a, float b, unsigned d){
  asm("v_cvt_pk_fp8_f32 %0, %1, %2" : "+v"(d) : "v"(a), "v"(b)); return d;
}
__device__ __forceinline__ unsigned pk8hi(float a, float b, unsigned d){
  asm("v_cvt_pk_fp8_f32 %0, %1, %2 op_sel:[0,0,1]" : "+v"(d) : "v"(a), "v"(b)); return d;
}
__device__ __forceinline__ unsigned char f2fp8(float f){
  unsigned d = 0;
  asm("v_cvt_pk_fp8_f32 %0, %1, %2" : "+v"(d) : "v"(f), "v"(0.f));
  return (unsigned char)(d & 0xFF);
}

// ---------------- K0: pack weights + vbufT pads + attn mask -----------------
__global__ __launch_bounds__(256) void wt_kernel(
    const float* __restrict__ fc1_w, const float* __restrict__ fc2_w,
    const float* __restrict__ proj_w, const float* __restrict__ q_w,
    const float* __restrict__ kv_w,
    unsigned char* __restrict__ W1F8, unsigned char* __restrict__ W2F8,
    bf16* __restrict__ PWF, bf16* __restrict__ QWF, bf16* __restrict__ KVF,
    bf16* __restrict__ vbufT, float* __restrict__ maskbuf){
  int gid = blockIdx.x*256 + threadIdx.x;
  if (gid < 262144){               // W1F8: K=256 (kc<8), N=1024 (nt<64)
    int e=gid&7, lane=(gid>>3)&63, kc=(gid>>9)&7, nt=gid>>12;
    int li=lane&15, lg=lane>>4;
    W1F8[gid] = f2fp8(fc1_w[(size_t)(kc*32+lg*8+e)*1024 + nt*16+li]);
  } else if (gid < 524288){        // W2F8: K=1024 (kc<32), N=256 (nt<16)
    int o = gid - 262144;
    int e=o&7, lane=(o>>3)&63, kc=(o>>9)&31, nt=o>>14;
    int li=lane&15, lg=lane>>4;
    W2F8[o] = f2fp8(fc2_w[(size_t)(kc*32+lg*8+e)*256 + nt*16+li]);
  } else if (gid < 589824){        // PWF: K=256 (kc<8), N=256 (nt<16)
    int o = gid - 524288;
    int e=o&7, lane=(o>>3)&63, kc=(o>>9)&7, nt=o>>12;
    int li=lane&15, lg=lane>>4;
    PWF[o] = f2bf(proj_w[(size_t)(kc*32+lg*8+e)*256 + nt*16+li]);
  } else if (gid < 655360){        // QWF: K=256, N=256, scaled by QSCALE
    int o = gid - 589824;
    int e=o&7, lane=(o>>3)&63, kc=(o>>9)&7, nt=o>>12;
    int li=lane&15, lg=lane>>4;
    QWF[o] = f2bf(q_w[(size_t)(kc*32+lg*8+e)*256 + nt*16+li] * QSCALE);
  } else if (gid < 786432){        // KVF: K=256, N=512 (nt<32)
    int o = gid - 655360;
    int e=o&7, lane=(o>>3)&63, kc=(o>>9)&7, nt=o>>12;
    int li=lane&15, lg=lane>>4;
    KVF[o] = f2bf(kv_w[(size_t)(kc*32+lg*8+e)*512 + nt*16+li]);
  } else {
    int idx = gid - 786432;
    if (idx < 7168){
      int row = idx/7, p = idx - row*7;
      vbufT[(size_t)row*736 + 729 + p] = f2bf(0.f);
    } else if (idx < 7680){
      vbufT[(size_t)1024*736 + (idx-7168)] = f2bf(0.f);  // hi-guard
    } else {
      int o = idx - 7680;            // 0..62207
      int wi2 = o / 768, local = o - wi2*768;
      int wh2 = wi2/9, ww2 = wi2 - wh2*9;
      int C2 = 81*wh2 + 3*ww2 - 336;
      int off2 = C2 & 7;
      int kk = local - off2;
      bool valid = ((unsigned)kk < 729u);
      int kr = valid ? kk/27 : 0;
      int kc2 = kk - kr*27;
      int gr = wh2*3 - 12 + kr, gc = ww2*3 - 12 + kc2;
      valid = valid && ((unsigned)gr < 27u) && ((unsigned)gc < 27u)
                    && !(gr >= 24 && gc >= 24);
      maskbuf[(size_t)wi2*768 + local] = valid ? 0.f : -30000.f;
    }
  }
}

// ---------------- K1: merged kv (blocks 0..365) + q (blocks 366..1358) ------
__global__ __launch_bounds__(256) void kvq_kernel(
    const float* __restrict__ y, const float* __restrict__ x,
    const float* __restrict__ g, const float* __restrict__ bb,
    const bf16* __restrict__ KVF, const bf16* __restrict__ QWF,
    bf16* __restrict__ kbuf, bf16* __restrict__ vbufT, bf16* __restrict__ qbuf){
  __shared__ __align__(16) unsigned short xn[16*256];  // swizzled bf16, 8 KB
  int tid = threadIdx.x, wid = tid>>6, lane = tid&63;
  int li = lane&15, lg = lane>>4;
  if (blockIdx.x < 366){
    int blk = blockIdx.x;
    int tok0 = (blk >> 1) * 16;
    int half = blk & 1;
    {
      float4 g4 = ((const float4*)g)[lane];
      float4 b4 = ((const float4*)bb)[lane];
      #pragma unroll
      for (int tt=0; tt<4; tt++){
        int t = wid*4 + tt;
        int gtok = tok0 + t;
        float4 v = make_float4(0.f,0.f,0.f,0.f);
        if (gtok < 2916) v = ((const float4*)(y + (size_t)gtok*256))[lane];
        float s = v.x+v.y+v.z+v.w, ss = v.x*v.x+v.y*v.y+v.z*v.z+v.w*v.w;
        #pragma unroll
        for (int off=32; off; off>>=1){ s += __shfl_xor(s,off); ss += __shfl_xor(ss,off); }
        float mean = s*(1.f/256.f);
        float var  = fmaxf(ss*(1.f/256.f) - mean*mean, 0.f);
        float inv  = rsqrtf(var + 1e-5f);
        ushort4 pk;
        pk.x = f2bfu((v.x-mean)*inv*g4.x+b4.x);
        pk.y = f2bfu((v.y-mean)*inv*g4.y+b4.y);
        pk.z = f2bfu((v.z-mean)*inv*g4.z+b4.z);
        pk.w = f2bfu((v.w-mean)*inv*g4.w+b4.w);
        int idx = (t*256 + lane*4) ^ ((t&7)<<3);
        *(ushort4*)&xn[idx] = pk;
      }
    }
    __syncthreads();
    bf16x8 a[8];
    #pragma unroll
    for (int ks=0; ks<8; ks++){
      int idx = (li*256 + ks*32 + lg*8) ^ ((li&7)<<3);
      a[ks] = *(const bf16x8*)&xn[idx];
    }
    #pragma unroll
    for (int nn=0; nn<4; nn++){
      int ntg = half*16 + wid*4 + nn;
      const bf16* wp = KVF + (size_t)ntg*4096 + lane*8;
      f32x4 acc = {0.f,0.f,0.f,0.f};
      #pragma unroll
      for (int ks=0; ks<8; ks++){
        bf16x8 bfrag = *(const bf16x8*)(wp + ks*512);
        acc = __builtin_amdgcn_mfma_f32_16x16x32_bf16(a[ks], bfrag, acc, 0, 0, 0);
      }
      int col = ntg*16 + li;
      #pragma unroll
      for (int r=0; r<4; r++){
        int tok = tok0 + lg*4 + r;
        if (tok < 2916){
          if (col < 256){
            kbuf[(size_t)tok*256 + col] = f2bf(acc[r]);
          } else {
            int b2 = (tok>=729) + (tok>=1458) + (tok>=2187);
            int ltok = tok - b2*729;
            vbufT[(size_t)(b2*256 + col-256)*736 + ltok] = f2bf(acc[r]);
          }
        }
      }
    }
  } else {
    int row0 = (blockIdx.x - 366) * 16;
    {
      float4 g4 = ((const float4*)g)[lane];
      float4 b4 = ((const float4*)bb)[lane];
      #pragma unroll
      for (int tt=0; tt<4; tt++){
        int t = wid*4 + tt;
        int row = row0 + t;
        float4 v = make_float4(0.f,0.f,0.f,0.f);
        if (row < 15876){
          int w = row/49, t2 = row - w*49;
          int b = w/81, wi = w - b*81;
          int wh = wi/9, ww = wi - wh*9;
          int r = t2/7, c = t2 - r*7;
          int gh = wh*7 + r, gw = ww*7 + c;
          if (gh < 60 && gw < 60)
            v = ((const float4*)(x + (size_t)(b*3600 + gh*60 + gw)*256))[lane];
        }
        float s=v.x+v.y+v.z+v.w, ss=v.x*v.x+v.y*v.y+v.z*v.z+v.w*v.w;
        #pragma unroll
        for (int off=32; off; off>>=1){ s += __shfl_xor(s,off); ss += __shfl_xor(ss,off); }
        float mean = s*(1.f/256.f);
        float var = fmaxf(ss*(1.f/256.f)-mean*mean, 0.f);
        float inv = rsqrtf(var+1e-5f);
        ushort4 pk;
        pk.x = f2bfu((v.x-mean)*inv*g4.x+b4.x);
        pk.y = f2bfu((v.y-mean)*inv*g4.y+b4.y);
        pk.z = f2bfu((v.z-mean)*inv*g4.z+b4.z);
        pk.w = f2bfu((v.w-mean)*inv*g4.w+b4.w);
        int idx = (t*256 + lane*4) ^ ((t&7)<<3);
        *(ushort4*)&xn[idx] = pk;
      }
    }
    __syncthreads();
    bf16x8 a[8];
    #pragma unroll
    for (int ks=0; ks<8; ks++){
      int idx = (li*256 + ks*32 + lg*8) ^ ((li&7)<<3);
      a[ks] = *(const bf16x8*)&xn[idx];
    }
    #pragma unroll
    for (int nt=0; nt<4; nt++){
      int ntg = wid*4 + nt;
      const bf16* wp = QWF + (size_t)ntg*4096 + lane*8;
      f32x4 acc = {0.f,0.f,0.f,0.f};
      #pragma unroll
      for (int ks=0; ks<8; ks++){
        bf16x8 bfrag = *(const bf16x8*)(wp + ks*512);
        acc = __builtin_amdgcn_mfma_f32_16x16x32_bf16(a[ks], bfrag, acc, 0, 0, 0);
      }
      int col = ntg*16 + li;
      #pragma unroll
      for (int r=0; r<4; r++){
        int row = row0 + lg*4 + r;
        if (row < 15876)
          qbuf[(size_t)row*256 + col] = f2bf(acc[r]);
      }
    }
  }
}

// ---------------- K3: swapped-QK^T attention, longest-first dispatch --------
__global__ __launch_bounds__(512) void attn_kernel(
    const bf16* __restrict__ qbuf, const bf16* __restrict__ kbuf,
    const bf16* __restrict__ vbufT, const float* __restrict__ maskbuf,
    bf16* __restrict__ obuf){
  __shared__ __align__(16) unsigned short Kls[2][4096];   // per-head frag-order K
  __shared__ __align__(16) unsigned short VlsF[2][8192];  // per-head frag-order V

  int tid = threadIdx.x;
  int sub = tid >> 8;
  int t256 = tid & 255;
  int wid = t256 >> 6, lane = tid & 63;
  int lg = lane>>4, li = lane&15;
  // Longest-first: wh groups {3,4,5}=6 tiles, {1,2,6}=5, {0,7,8}=4; each wh
  // accounts for 144 blocks (4 batches x 9 ww x 4 head-pairs). Bijective.
  static const int whmap[9] = {3,4,5, 1,2,6, 0,7,8};
  int s_ = blockIdx.x;
  int gidx = s_ / 144, rem = s_ - gidx*144;
  int wh = whmap[gidx];
  int b = rem / 36, rr = rem - b*36;
  int ww = rr >> 2, hp = rr & 3;
  int wi = wh*9 + ww;
  int w = b*81 + wi;
  int hh = hp*2 + sub;

  int C  = 81*wh + 3*ww - 336;
  int T0 = C & ~7, off = C & 7;
  int kr_min = 12 - 3*wh; if (kr_min < 0) kr_min = 0;
  int kr_max = 39 - 3*wh; if (kr_max > 27) kr_max = 27;
  int t0 = (kr_min*27 + off) >> 7;
  int t1 = (kr_max*27 + off + 127) >> 7;   // window-level: same for both subs

  const bf16* kb  = kbuf  + (long long)(b*729 + T0)*256 + hh*32;
  const bf16* vbT = vbufT + (long long)(b*256 + hh*32)*736 + T0;
  const float* mk = maskbuf + wi*768;

  const bf16* ksrcA = kb + (long long)(2*wid*16 + li)*256 + lg*8;
  const bf16* ksrcB = kb + (long long)((2*wid+1)*16 + li)*256 + lg*8;
  int vrow = t256>>4, vch = t256&15;
  const bf16* vsrcA = vbT + (long long)vrow*736 + vch*8;
  const bf16* vsrcB = vbT + (long long)(vrow+16)*736 + vch*8;
  int vc_ = vch>>2, vhalf = (vch>>1)&1, vlg0 = (vch&1)*2;
  unsigned vdst0 = (unsigned)(((vc_*64 + vlg0*16     + vrow)*16 + vhalf*8) ^ (vc_<<5));
  unsigned vdst1 = (unsigned)(((vc_*64 + (vlg0+1)*16 + vrow)*16 + vhalf*8) ^ (vc_<<5));
  char* Vbase = (char*)&VlsF[sub][0];
  unsigned short* Kbase = &Kls[sub][0];

  bf16x8 qf;
  #pragma unroll
  for (int e=0;e<8;e++) qf[e]=0;
  int qrow = wid*16 + li;
  if (qrow < 49)
    qf = *(const bf16x8*)(qbuf + ((size_t)w*49+qrow)*256 + hh*32 + lg*8);

  f32x4 o0 = {0.f,0.f,0.f,0.f}, o1 = {0.f,0.f,0.f,0.f};
  float m = -3.0e38f, l = 0.f;

  {
    int j0 = t0*128;
    uint4 k0 = *(const uint4*)(ksrcA + (long long)j0*256);
    uint4 k1 = *(const uint4*)(ksrcB + (long long)j0*256);
    uint4 v0 = *(const uint4*)(vsrcA + j0);
    uint4 v1 = *(const uint4*)(vsrcB + j0);
    *(uint4*)&Kbase[2*wid*512 + lane*8]     = k0;
    *(uint4*)&Kbase[(2*wid+1)*512 + lane*8] = k1;
    *(uint2*)(Vbase + vdst0)        = make_uint2(v0.x, v0.y);
    *(uint2*)(Vbase + vdst1)        = make_uint2(v0.z, v0.w);
    *(uint2*)(Vbase + 8192 + vdst0) = make_uint2(v1.x, v1.y);
    *(uint2*)(Vbase + 8192 + vdst1) = make_uint2(v1.z, v1.w);
  }
  __syncthreads();

  for (int tile=t0; tile<t1; tile++){
    int jbase = tile*128;
    uint4 nk0, nk1, nv0, nv1;
    if (tile+1 < t1){
      int jn = jbase + 128;
      nk0 = *(const uint4*)(ksrcA + (long long)jn*256);
      nk1 = *(const uint4*)(ksrcB + (long long)jn*256);
      nv0 = *(const uint4*)(vsrcA + jn);
      nv1 = *(const uint4*)(vsrcB + jn);
    }
    __builtin_amdgcn_s_setprio(1);
    f32x4 s[8];
    #pragma unroll
    for (int t=0;t<8;t++){
      bf16x8 kf = *(const bf16x8*)&Kbase[t*512 + lane*8];
      float4 mv = *(const float4*)(mk + jbase + t*16 + lg*4);
      f32x4 cin = {mv.x, mv.y, mv.z, mv.w};
      s[t] = __builtin_amdgcn_mfma_f32_16x16x32_bf16(kf, qf, cin, 0, 0, 0);
    }
    float m0 = fmaxf(fmaxf(s[0][0], s[0][1]), fmaxf(s[0][2], s[0][3]));
    float m1 = fmaxf(fmaxf(s[1][0], s[1][1]), fmaxf(s[1][2], s[1][3]));
    float m2 = fmaxf(fmaxf(s[2][0], s[2][1]), fmaxf(s[2][2], s[2][3]));
    float m3 = fmaxf(fmaxf(s[3][0], s[3][1]), fmaxf(s[3][2], s[3][3]));
    float m4 = fmaxf(fmaxf(s[4][0], s[4][1]), fmaxf(s[4][2], s[4][3]));
    float m5 = fmaxf(fmaxf(s[5][0], s[5][1]), fmaxf(s[5][2], s[5][3]));
    float m6 = fmaxf(fmaxf(s[6][0], s[6][1]), fmaxf(s[6][2], s[6][3]));
    float m7 = fmaxf(fmaxf(s[7][0], s[7][1]), fmaxf(s[7][2], s[7][3]));
    float mt = fmaxf(fmaxf(fmaxf(m0, m1), fmaxf(m2, m3)),
                     fmaxf(fmaxf(m4, m5), fmaxf(m6, m7)));
    mt = fmaxf(mt, __shfl_xor(mt, 16));
    mt = fmaxf(mt, __shfl_xor(mt, 32));
    if (!__all(mt - m <= 8.f)){
      float mn = fmaxf(m, mt);
      float fac = fexp2(m - mn);
      m = mn;
      l *= fac;
      #pragma unroll
      for (int r=0;r<4;r++){ o0[r] *= fac; o1[r] *= fac; }
    }
    float ps = 0.f;
    #pragma unroll
    for (int t=0;t<8;t++){
      #pragma unroll
      for (int r=0;r<4;r++){
        float p = fexp2(s[t][r] - m);
        s[t][r] = p;
        ps += p;
      }
    }
    ps += __shfl_xor(ps, 16);
    ps += __shfl_xor(ps, 32);
    l += ps;
    unsigned pk[8][2];
    #pragma unroll
    for (int t=0;t<8;t++){
      pk[t][0] = cvtpk(s[t][0], s[t][1]);
      pk[t][1] = cvtpk(s[t][2], s[t][3]);
    }
    #pragma unroll
    for (int c=0;c<4;c++){
      union { unsigned u[4]; bf16x8 v; } pb;
      pb.u[0]=pk[2*c][0];   pb.u[1]=pk[2*c][1];
      pb.u[2]=pk[2*c+1][0]; pb.u[3]=pk[2*c+1][1];
      unsigned offb = (unsigned)(((c*64 + lg*16 + li)*16) ^ (c<<5));
      bf16x8 va = *(const bf16x8*)(Vbase + offb);
      bf16x8 vcf = *(const bf16x8*)(Vbase + 8192 + offb);
      o0 = __builtin_amdgcn_mfma_f32_16x16x32_bf16(va,  pb.v, o0, 0, 0, 0);
      o1 = __builtin_amdgcn_mfma_f32_16x16x32_bf16(vcf, pb.v, o1, 0, 0, 0);
    }
    __builtin_amdgcn_s_setprio(0);
    if (tile+1 < t1){
      __syncthreads();
      *(uint4*)&Kbase[2*wid*512 + lane*8]     = nk0;
      *(uint4*)&Kbase[(2*wid+1)*512 + lane*8] = nk1;
      *(uint2*)(Vbase + vdst0)        = make_uint2(nv0.x, nv0.y);
      *(uint2*)(Vbase + vdst1)        = make_uint2(nv0.z, nv0.w);
      *(uint2*)(Vbase + 8192 + vdst0) = make_uint2(nv1.x, nv1.y);
      *(uint2*)(Vbase + 8192 + vdst1) = make_uint2(nv1.z, nv1.w);
      __syncthreads();
    }
  }

  if (qrow < 49){
    float rl = 1.f / l;
    bf16* op = obuf + ((size_t)w*49 + qrow)*256 + hh*32;
    unsigned da0 = cvtpk(o0[0]*rl, o0[1]*rl);
    unsigned da1 = cvtpk(o0[2]*rl, o0[3]*rl);
    unsigned db0 = cvtpk(o1[0]*rl, o1[1]*rl);
    unsigned db1 = cvtpk(o1[2]*rl, o1[3]*rl);
    *(uint2*)(op + lg*4)      = make_uint2(da0, da1);
    *(uint2*)(op + 16 + lg*4) = make_uint2(db0, db1);
  }
}

// ---------------- K4: FUSED proj+MLP, 2-subtile blocks, 2-deep W pipelines --
__global__ __launch_bounds__(512) void projmlp_kernel(
    const bf16* __restrict__ obuf, const float* __restrict__ x,
    const bf16* __restrict__ PWF, const float* __restrict__ proj_b,
    const float* __restrict__ ls1,
    const float* __restrict__ g, const float* __restrict__ bb,
    const unsigned char* __restrict__ W1F8, const float* __restrict__ fc1_b,
    const unsigned char* __restrict__ W2F8, const float* __restrict__ fc2_b,
    const float* __restrict__ ls2, float* __restrict__ out){
  __shared__ __align__(16) unsigned char xn8[2][4096];   // fp8, 2 x 4 KB
  __shared__ __align__(16) char ubuf[2][16640];          // per-sub: xo_ls | Hls8
  int tid = threadIdx.x;
  int sub = tid >> 8;
  int t256 = tid & 255;
  int wid = t256 >> 6, lane = tid & 63;
  int li = lane&15, lg = lane>>4;
  int pix0 = blockIdx.x * 32 + sub * 16;
  float* xo_ls = (float*)&ubuf[sub][0];
  unsigned char* Hls8 = (unsigned char*)&ubuf[sub][0];
  unsigned char* xn8s = &xn8[sub][0];

  // ---- Phase A: proj (bf16). A-frags + x residuals loaded up front ----
  bf16x8 a[8];
  {
    int pixA = pix0 + li;
    int b = pixA/3600, rem = pixA - b*3600;
    int gh = rem/60, gw = rem - gh*60;
    int w = b*81 + (gh/7)*9 + (gw/7);
    int t = (gh%7)*7 + (gw%7);
    long long wrow = (long long)w*49 + t;
    #pragma unroll
    for (int ks=0; ks<8; ks++)
      a[ks] = *(const bf16x8*)(obuf + wrow*256 + ks*32 + lg*8);
  }
  float pbv[4], l1v[4], l2v[4], cbv[4], xr[4][4];
  #pragma unroll
  for (int nt=0; nt<4; nt++){
    int col = wid*64 + nt*16 + li;
    pbv[nt] = proj_b[col];
    l1v[nt] = ls1[col];
    l2v[nt] = ls2[col];
    cbv[nt] = fc2_b[col];
    #pragma unroll
    for (int r=0; r<4; r++)
      xr[nt][r] = x[(size_t)(pix0 + lg*4 + r)*256 + col];  // issued early
  }
  float xov[4][4];
  #pragma unroll
  for (int nt=0; nt<4; nt++){
    const bf16* wp = PWF + (size_t)(wid*4 + nt)*4096 + lane*8;
    f32x4 z = {0.f,0.f,0.f,0.f};
    #pragma unroll
    for (int ks=0; ks<8; ks++){
      bf16x8 bfrag = *(const bf16x8*)(wp + ks*512);
      z = __builtin_amdgcn_mfma_f32_16x16x32_bf16(a[ks], bfrag, z, 0, 0, 0);
    }
    int col = wid*64 + nt*16 + li;
    #pragma unroll
    for (int r=0; r<4; r++){
      float xo = xr[nt][r] + l1v[nt]*(z[r] + pbv[nt]);
      xov[nt][r] = xo;
      xo_ls[(lg*4 + r)*260 + col] = xo;
    }
  }
  __syncthreads();
  // ---- Phase B: LN of 16 rows -> xn8 (fp8, byte swizzle ^(t&3)<<3) ----
  {
    float4 g4 = ((const float4*)g)[lane];
    float4 b4 = ((const float4*)bb)[lane];
    #pragma unroll
    for (int tt=0; tt<4; tt++){
      int t = wid*4 + tt;
      float4 v = *(const float4*)&xo_ls[t*260 + lane*4];
      float s = v.x+v.y+v.z+v.w;
      float ss = v.x*v.x+v.y*v.y+v.z*v.z+v.w*v.w;
      #pragma unroll
      for (int off=32; off; off>>=1){ s += __shfl_xor(s,off); ss += __shfl_xor(ss,off); }
      float mean = s*(1.f/256.f);
      float var = fmaxf(ss*(1.f/256.f)-mean*mean, 0.f);
      float inv = rsqrtf(var+1e-5f);
      unsigned d = 0;
      d = pk8lo((v.x-mean)*inv*g4.x+b4.x, (v.y-mean)*inv*g4.y+b4.y, d);
      d = pk8hi((v.z-mean)*inv*g4.z+b4.z, (v.w-mean)*inv*g4.w+b4.w, d);
      *(unsigned*)&xn8s[t*256 + ((lane*4) ^ ((t&3)<<3))] = d;
    }
  }
  __syncthreads();
  long a1[8];
  #pragma unroll
  for (int ks=0; ks<8; ks++)
    a1[ks] = *(const long*)&xn8s[li*256 + ks*32 + ((lg*8) ^ ((li&3)<<3))];
  // NOTE: Hls8 overwrites xo_ls from here on (xov keeps the residual in regs).
  // ---- Phase C: fp8 fc1 SWAPPED + GELU -> Hls8; 2-deep mod-3 W pipeline ----
  const unsigned char* w1base = W1F8 + (size_t)(wid*16)*4096 + lane*8;
  long w1p[3][8];
  #pragma unroll
  for (int ks=0; ks<8; ks++){
    w1p[0][ks] = *(const long*)(w1base + ks*512);
    w1p[1][ks] = *(const long*)(w1base + 4096 + ks*512);
  }
  #pragma unroll
  for (int nn=0; nn<16; nn++){
    if (nn < 14){
      const unsigned char* wpn = w1base + (size_t)(nn+2)*4096;
      #pragma unroll
      for (int ks=0; ks<8; ks++) w1p[(nn+2)%3][ks] = *(const long*)(wpn + ks*512);
    }
    // SWAPPED: D[row = h-col (lg*4+r) within tile][col = token li]
    __builtin_amdgcn_s_setprio(1);
    f32x4 hc = {0.f,0.f,0.f,0.f};
    #pragma unroll
    for (int ks=0; ks<8; ks++)
      hc = __builtin_amdgcn_mfma_f32_16x16x32_fp8_fp8(w1p[nn%3][ks], a1[ks], hc, 0, 0, 0);
    __builtin_amdgcn_s_setprio(0);
    int ntg = wid*16 + nn;
    float4 bias4 = *(const float4*)&fc1_b[ntg*16 + lg*4];
    float gv[4];
    #pragma unroll
    for (int r=0; r<4; r++){
      float h = hc[r] + ((const float*)&bias4)[r];
      float z = 0.7978845608f*(h + 0.044715f*h*h*h);   // tanh-approx GELU
      z = fminf(fmaxf(z, -15.f), 15.f);
      float e = __expf(2.f*z);
      gv[r] = 0.5f*h*(1.f + (e-1.f)/(e+1.f));
    }
    unsigned d = 0;
    d = pk8lo(gv[0], gv[1], d);
    d = pk8hi(gv[2], gv[3], d);
    // H[token=li][hcols ntg*16 + lg*4 .. +3], 16B-group swizzle ntg^(li&7)
    *(unsigned*)&Hls8[li*1024 + ((ntg ^ (li&7))<<4) + lg*4] = d;
  }
  __syncthreads();
  // ---- Phase D: fp8 fc2; 2-deep mod-3 pipelines for h and W2 + epilogue ----
  f32x4 oacc[4];
  #pragma unroll
  for (int nt=0; nt<4; nt++) oacc[nt] = (f32x4){0.f,0.f,0.f,0.f};
  long hp3[3], w2p[3][4];
  {
    hp3[0] = *(const long*)&Hls8[li*1024 + (((0 + (lg>>1)) ^ (li&7))<<4) + (lg&1)*8];
    hp3[1] = *(const long*)&Hls8[li*1024 + (((2 + (lg>>1)) ^ (li&7))<<4) + (lg&1)*8];
    #pragma unroll
    for (int nt=0; nt<4; nt++){
      w2p[0][nt] = *(const long*)(W2F8 + ((size_t)(wid*4+nt)*32)*512 + lane*8);
      w2p[1][nt] = *(const long*)(W2F8 + ((size_t)(wid*4+nt)*32 + 1)*512 + lane*8);
    }
  }
  #pragma unroll
  for (int kc=0; kc<32; kc++){
    if (kc < 30){
      hp3[(kc+2)%3] = *(const long*)&Hls8[li*1024 + (((2*(kc+2) + (lg>>1)) ^ (li&7))<<4) + (lg&1)*8];
      #pragma unroll
      for (int nt=0; nt<4; nt++)
        w2p[(kc+2)%3][nt] = *(const long*)(W2F8 + ((size_t)(wid*4+nt)*32 + kc+2)*512 + lane*8);
    }
    __builtin_amdgcn_s_setprio(1);
    #pragma unroll
    for (int nt=0; nt<4; nt++)
      oacc[nt] = __builtin_amdgcn_mfma_f32_16x16x32_fp8_fp8(hp3[kc%3], w2p[kc%3][nt], oacc[nt], 0, 0, 0);
    __builtin_amdgcn_s_setprio(0);
  }
  #pragma unroll
  for (int nt=0; nt<4; nt++){
    int col = wid*64 + nt*16 + li;
    #pragma unroll
    for (int r=0; r<4; r++){
      size_t p = (size_t)(pix0 + lg*4 + r)*256 + col;
      out[p] = xov[nt][r] + l2v[nt]*(oacc[nt][r] + cbv[nt]);
    }
  }
}

extern "C" void kernel_launch(void* const* d_in, const int* in_sizes, int n_in,
                              void* d_out, int out_size, void* d_ws, size_t ws_size,
                              hipStream_t stream) {
  (void)in_sizes; (void)n_in; (void)out_size; (void)ws_size;
  const float* x      = (const float*)d_in[0];
  const float* y      = (const float*)d_in[1];
  const float* n1g    = (const float*)d_in[2];
  const float* n1b    = (const float*)d_in[3];
  const float* q_w    = (const float*)d_in[4];
  const float* kv_w   = (const float*)d_in[5];
  const float* proj_w = (const float*)d_in[6];
  const float* proj_b = (const float*)d_in[7];
  const float* n2g    = (const float*)d_in[8];
  const float* n2b    = (const float*)d_in[9];
  const float* fc1_w  = (const float*)d_in[10];
  const float* fc1_b  = (const float*)d_in[11];
  const float* fc2_w  = (const float*)d_in[12];
  const float* fc2_b  = (const float*)d_in[13];
  const float* ls1    = (const float*)d_in[14];
  const float* ls2    = (const float*)d_in[15];

  char* ws = (char*)d_ws;
  // Workspace (24.17 MB):
  //   qbuf  bf16[324*49*256]   @ 0          live K1..K3 (also K lo-guard: finite)
  //   kbuf  bf16[2916*256]     @ 8,128,512  live K1..K3
  //   vbufT bf16[1024*736+512] @ 9,621,504  live K1..K3 (pads zeroed by K0)
  //   obuf  bf16[324*49*256]   @ 14,745,600 live K3..K4
  //   W1F8 u8[262144] @22,874,112   W2F8 u8[262144] @23,136,256
  //   PWF bf16[65536] @23,398,400   QWF bf16[65536] @23,529,472
  //   KVF bf16[131072] @23,660,544  maskbuf f32[81*768] @23,922,688 (ends 24,171,520)
  bf16*  qbuf  = (bf16*)(ws);
  bf16*  kbuf  = (bf16*)(ws + 8128512);
  bf16*  vbufT = (bf16*)(ws + 9621504);
  bf16*  obuf  = (bf16*)(ws + 14745600);
  unsigned char* W1F8 = (unsigned char*)(ws + 22874112);
  unsigned char* W2F8 = (unsigned char*)(ws + 23136256);
  bf16*  PWF   = (bf16*)(ws + 23398400);
  bf16*  QWF   = (bf16*)(ws + 23529472);
  bf16*  KVF   = (bf16*)(ws + 23660544);
  float* maskbuf = (float*)(ws + 23922688);

  wt_kernel<<<3345, 256, 0, stream>>>(fc1_w, fc2_w, proj_w, q_w, kv_w,
                                      W1F8, W2F8, PWF, QWF, KVF, vbufT, maskbuf);
  kvq_kernel<<<1359, 256, 0, stream>>>(y, x, n1g, n1b, KVF, QWF,
                                       kbuf, vbufT, qbuf);
  attn_kernel<<<1296, 512, 0, stream>>>(qbuf, kbuf, vbufT, maskbuf, obuf);
  projmlp_kernel<<<450, 512, 0, stream>>>(obuf, x, PWF, proj_b, ls1,
                                          n2g, n2b, W1F8, fc1_b, W2F8, fc2_b, ls2,
                                          (float*)d_out);
}

// Round 25
// 116.260 us; speedup vs baseline: 1.0509x; 1.0509x over previous
//
#include <hip/hip_runtime.h>
#include <hip/hip_bf16.h>

typedef __hip_bfloat16 bf16;
typedef __attribute__((ext_vector_type(8))) short bf16x8;
typedef __attribute__((ext_vector_type(4))) float f32x4;

// Problem constants: B=4, H=W=60, C=256, HEADS=8, hd=32, WS=7 -> 9x9 windows/batch,
// 324 windows, 49 q/window, key window 27x27=729 gathered from the 27x27 stride-3
// grid. KEY IDENTITY: token = kk + C with C = 81*wh + 3*ww - 336 -> contiguous
// token slice; invalid keys killed by precomputed ADDITIVE mask (-30000).
// All external I/O f32; staging bf16 (attn) / fp8-e4m3 (MLP). Softmax in log2
// domain (q pre-scaled by hd^-0.5*log2(e); exp = v_exp_f32).
//
// Verified MFMA lane mapping (16x16x32, rounds 3-24):
//   A-frag: lane(li=lane&15, lg=lane>>4) holds A[row=li][k=lg*8+e (mod 32)]
//   B-frag: lane holds B[col=li][k=lg*8+e]
//   C/D   : [row=lg*4+r][col=li]   (dtype-independent on gfx950)
// fp8 note: A and B are packed with the SAME assumed (lg,e)->k byte order, so
// any HW k-permutation cancels in the contraction.
// Round 25: REVERT projmlp to the round-23 optimum (1-deep prefetch, no
// in-loop setprio) — r24's 2-deep mod-3 pipeline dropped occupancy 26->17%
// and fragmented scheduling (-11%). r23 config = best measured: 116.5 us.

#define QSCALE 0.25505402616302864f  // (1/sqrt(32)) * log2(e)

__device__ __forceinline__ bf16 f2bf(float f){ return __float2bfloat16(f); }
__device__ __forceinline__ unsigned short f2bfu(float f){
  __hip_bfloat16 h = __float2bfloat16(f);
  return *(unsigned short*)&h;
}
__device__ __forceinline__ float fexp2(float x){
  float r; asm("v_exp_f32 %0, %1" : "=v"(r) : "v"(x)); return r;
}
__device__ __forceinline__ unsigned cvtpk(float lo, float hi){
  unsigned r; asm("v_cvt_pk_bf16_f32 %0, %1, %2" : "=v"(r) : "v"(lo), "v"(hi));
  return r;
}
// f32 -> fp8 e4m3 (OCP on gfx950). pk writes 2 bytes; lo = bits 15:0, hi = 31:16.
__device__ __forceinline__ unsigned pk8lo(float a, float b, unsigned d){
  asm("v_cvt_pk_fp8_f32 %0, %1, %2" : "+v"(d) : "v"(a), "v"(b)); return d;
}
__device__ __forceinline__ unsigned pk8hi(float a, float b, unsigned d){
  asm("v_cvt_pk_fp8_f32 %0, %1, %2 op_sel:[0,0,1]" : "+v"(d) : "v"(a), "v"(b)); return d;
}
__device__ __forceinline__ unsigned char f2fp8(float f){
  unsigned d = 0;
  asm("v_cvt_pk_fp8_f32 %0, %1, %2" : "+v"(d) : "v"(f), "v"(0.f));
  return (unsigned char)(d & 0xFF);
}

// ---------------- K0: pack weights + vbufT pads + attn mask -----------------
__global__ __launch_bounds__(256) void wt_kernel(
    const float* __restrict__ fc1_w, const float* __restrict__ fc2_w,
    const float* __restrict__ proj_w, const float* __restrict__ q_w,
    const float* __restrict__ kv_w,
    unsigned char* __restrict__ W1F8, unsigned char* __restrict__ W2F8,
    bf16* __restrict__ PWF, bf16* __restrict__ QWF, bf16* __restrict__ KVF,
    bf16* __restrict__ vbufT, float* __restrict__ maskbuf){
  int gid = blockIdx.x*256 + threadIdx.x;
  if (gid < 262144){               // W1F8: K=256 (kc<8), N=1024 (nt<64)
    int e=gid&7, lane=(gid>>3)&63, kc=(gid>>9)&7, nt=gid>>12;
    int li=lane&15, lg=lane>>4;
    W1F8[gid] = f2fp8(fc1_w[(size_t)(kc*32+lg*8+e)*1024 + nt*16+li]);
  } else if (gid < 524288){        // W2F8: K=1024 (kc<32), N=256 (nt<16)
    int o = gid - 262144;
    int e=o&7, lane=(o>>3)&63, kc=(o>>9)&31, nt=o>>14;
    int li=lane&15, lg=lane>>4;
    W2F8[o] = f2fp8(fc2_w[(size_t)(kc*32+lg*8+e)*256 + nt*16+li]);
  } else if (gid < 589824){        // PWF: K=256 (kc<8), N=256 (nt<16)
    int o = gid - 524288;
    int e=o&7, lane=(o>>3)&63, kc=(o>>9)&7, nt=o>>12;
    int li=lane&15, lg=lane>>4;
    PWF[o] = f2bf(proj_w[(size_t)(kc*32+lg*8+e)*256 + nt*16+li]);
  } else if (gid < 655360){        // QWF: K=256, N=256, scaled by QSCALE
    int o = gid - 589824;
    int e=o&7, lane=(o>>3)&63, kc=(o>>9)&7, nt=o>>12;
    int li=lane&15, lg=lane>>4;
    QWF[o] = f2bf(q_w[(size_t)(kc*32+lg*8+e)*256 + nt*16+li] * QSCALE);
  } else if (gid < 786432){        // KVF: K=256, N=512 (nt<32)
    int o = gid - 655360;
    int e=o&7, lane=(o>>3)&63, kc=(o>>9)&7, nt=o>>12;
    int li=lane&15, lg=lane>>4;
    KVF[o] = f2bf(kv_w[(size_t)(kc*32+lg*8+e)*512 + nt*16+li]);
  } else {
    int idx = gid - 786432;
    if (idx < 7168){
      int row = idx/7, p = idx - row*7;
      vbufT[(size_t)row*736 + 729 + p] = f2bf(0.f);
    } else if (idx < 7680){
      vbufT[(size_t)1024*736 + (idx-7168)] = f2bf(0.f);  // hi-guard
    } else {
      int o = idx - 7680;            // 0..62207
      int wi2 = o / 768, local = o - wi2*768;
      int wh2 = wi2/9, ww2 = wi2 - wh2*9;
      int C2 = 81*wh2 + 3*ww2 - 336;
      int off2 = C2 & 7;
      int kk = local - off2;
      bool valid = ((unsigned)kk < 729u);
      int kr = valid ? kk/27 : 0;
      int kc2 = kk - kr*27;
      int gr = wh2*3 - 12 + kr, gc = ww2*3 - 12 + kc2;
      valid = valid && ((unsigned)gr < 27u) && ((unsigned)gc < 27u)
                    && !(gr >= 24 && gc >= 24);
      maskbuf[(size_t)wi2*768 + local] = valid ? 0.f : -30000.f;
    }
  }
}

// ---------------- K1: merged kv (blocks 0..365) + q (blocks 366..1358) ------
__global__ __launch_bounds__(256) void kvq_kernel(
    const float* __restrict__ y, const float* __restrict__ x,
    const float* __restrict__ g, const float* __restrict__ bb,
    const bf16* __restrict__ KVF, const bf16* __restrict__ QWF,
    bf16* __restrict__ kbuf, bf16* __restrict__ vbufT, bf16* __restrict__ qbuf){
  __shared__ __align__(16) unsigned short xn[16*256];  // swizzled bf16, 8 KB
  int tid = threadIdx.x, wid = tid>>6, lane = tid&63;
  int li = lane&15, lg = lane>>4;
  if (blockIdx.x < 366){
    int blk = blockIdx.x;
    int tok0 = (blk >> 1) * 16;
    int half = blk & 1;
    {
      float4 g4 = ((const float4*)g)[lane];
      float4 b4 = ((const float4*)bb)[lane];
      #pragma unroll
      for (int tt=0; tt<4; tt++){
        int t = wid*4 + tt;
        int gtok = tok0 + t;
        float4 v = make_float4(0.f,0.f,0.f,0.f);
        if (gtok < 2916) v = ((const float4*)(y + (size_t)gtok*256))[lane];
        float s = v.x+v.y+v.z+v.w, ss = v.x*v.x+v.y*v.y+v.z*v.z+v.w*v.w;
        #pragma unroll
        for (int off=32; off; off>>=1){ s += __shfl_xor(s,off); ss += __shfl_xor(ss,off); }
        float mean = s*(1.f/256.f);
        float var  = fmaxf(ss*(1.f/256.f) - mean*mean, 0.f);
        float inv  = rsqrtf(var + 1e-5f);
        ushort4 pk;
        pk.x = f2bfu((v.x-mean)*inv*g4.x+b4.x);
        pk.y = f2bfu((v.y-mean)*inv*g4.y+b4.y);
        pk.z = f2bfu((v.z-mean)*inv*g4.z+b4.z);
        pk.w = f2bfu((v.w-mean)*inv*g4.w+b4.w);
        int idx = (t*256 + lane*4) ^ ((t&7)<<3);
        *(ushort4*)&xn[idx] = pk;
      }
    }
    __syncthreads();
    bf16x8 a[8];
    #pragma unroll
    for (int ks=0; ks<8; ks++){
      int idx = (li*256 + ks*32 + lg*8) ^ ((li&7)<<3);
      a[ks] = *(const bf16x8*)&xn[idx];
    }
    #pragma unroll
    for (int nn=0; nn<4; nn++){
      int ntg = half*16 + wid*4 + nn;
      const bf16* wp = KVF + (size_t)ntg*4096 + lane*8;
      f32x4 acc = {0.f,0.f,0.f,0.f};
      #pragma unroll
      for (int ks=0; ks<8; ks++){
        bf16x8 bfrag = *(const bf16x8*)(wp + ks*512);
        acc = __builtin_amdgcn_mfma_f32_16x16x32_bf16(a[ks], bfrag, acc, 0, 0, 0);
      }
      int col = ntg*16 + li;
      #pragma unroll
      for (int r=0; r<4; r++){
        int tok = tok0 + lg*4 + r;
        if (tok < 2916){
          if (col < 256){
            kbuf[(size_t)tok*256 + col] = f2bf(acc[r]);
          } else {
            int b2 = (tok>=729) + (tok>=1458) + (tok>=2187);
            int ltok = tok - b2*729;
            vbufT[(size_t)(b2*256 + col-256)*736 + ltok] = f2bf(acc[r]);
          }
        }
      }
    }
  } else {
    int row0 = (blockIdx.x - 366) * 16;
    {
      float4 g4 = ((const float4*)g)[lane];
      float4 b4 = ((const float4*)bb)[lane];
      #pragma unroll
      for (int tt=0; tt<4; tt++){
        int t = wid*4 + tt;
        int row = row0 + t;
        float4 v = make_float4(0.f,0.f,0.f,0.f);
        if (row < 15876){
          int w = row/49, t2 = row - w*49;
          int b = w/81, wi = w - b*81;
          int wh = wi/9, ww = wi - wh*9;
          int r = t2/7, c = t2 - r*7;
          int gh = wh*7 + r, gw = ww*7 + c;
          if (gh < 60 && gw < 60)
            v = ((const float4*)(x + (size_t)(b*3600 + gh*60 + gw)*256))[lane];
        }
        float s=v.x+v.y+v.z+v.w, ss=v.x*v.x+v.y*v.y+v.z*v.z+v.w*v.w;
        #pragma unroll
        for (int off=32; off; off>>=1){ s += __shfl_xor(s,off); ss += __shfl_xor(ss,off); }
        float mean = s*(1.f/256.f);
        float var = fmaxf(ss*(1.f/256.f)-mean*mean, 0.f);
        float inv = rsqrtf(var+1e-5f);
        ushort4 pk;
        pk.x = f2bfu((v.x-mean)*inv*g4.x+b4.x);
        pk.y = f2bfu((v.y-mean)*inv*g4.y+b4.y);
        pk.z = f2bfu((v.z-mean)*inv*g4.z+b4.z);
        pk.w = f2bfu((v.w-mean)*inv*g4.w+b4.w);
        int idx = (t*256 + lane*4) ^ ((t&7)<<3);
        *(ushort4*)&xn[idx] = pk;
      }
    }
    __syncthreads();
    bf16x8 a[8];
    #pragma unroll
    for (int ks=0; ks<8; ks++){
      int idx = (li*256 + ks*32 + lg*8) ^ ((li&7)<<3);
      a[ks] = *(const bf16x8*)&xn[idx];
    }
    #pragma unroll
    for (int nt=0; nt<4; nt++){
      int ntg = wid*4 + nt;
      const bf16* wp = QWF + (size_t)ntg*4096 + lane*8;
      f32x4 acc = {0.f,0.f,0.f,0.f};
      #pragma unroll
      for (int ks=0; ks<8; ks++){
        bf16x8 bfrag = *(const bf16x8*)(wp + ks*512);
        acc = __builtin_amdgcn_mfma_f32_16x16x32_bf16(a[ks], bfrag, acc, 0, 0, 0);
      }
      int col = ntg*16 + li;
      #pragma unroll
      for (int r=0; r<4; r++){
        int row = row0 + lg*4 + r;
        if (row < 15876)
          qbuf[(size_t)row*256 + col] = f2bf(acc[r]);
      }
    }
  }
}

// ---------------- K3: swapped-QK^T attention, longest-first dispatch --------
__global__ __launch_bounds__(512) void attn_kernel(
    const bf16* __restrict__ qbuf, const bf16* __restrict__ kbuf,
    const bf16* __restrict__ vbufT, const float* __restrict__ maskbuf,
    bf16* __restrict__ obuf){
  __shared__ __align__(16) unsigned short Kls[2][4096];   // per-head frag-order K
  __shared__ __align__(16) unsigned short VlsF[2][8192];  // per-head frag-order V

  int tid = threadIdx.x;
  int sub = tid >> 8;
  int t256 = tid & 255;
  int wid = t256 >> 6, lane = tid & 63;
  int lg = lane>>4, li = lane&15;
  // Longest-first: wh groups {3,4,5}=6 tiles, {1,2,6}=5, {0,7,8}=4; each wh
  // accounts for 144 blocks (4 batches x 9 ww x 4 head-pairs). Bijective.
  static const int whmap[9] = {3,4,5, 1,2,6, 0,7,8};
  int s_ = blockIdx.x;
  int gidx = s_ / 144, rem = s_ - gidx*144;
  int wh = whmap[gidx];
  int b = rem / 36, rr = rem - b*36;
  int ww = rr >> 2, hp = rr & 3;
  int wi = wh*9 + ww;
  int w = b*81 + wi;
  int hh = hp*2 + sub;

  int C  = 81*wh + 3*ww - 336;
  int T0 = C & ~7, off = C & 7;
  int kr_min = 12 - 3*wh; if (kr_min < 0) kr_min = 0;
  int kr_max = 39 - 3*wh; if (kr_max > 27) kr_max = 27;
  int t0 = (kr_min*27 + off) >> 7;
  int t1 = (kr_max*27 + off + 127) >> 7;   // window-level: same for both subs

  const bf16* kb  = kbuf  + (long long)(b*729 + T0)*256 + hh*32;
  const bf16* vbT = vbufT + (long long)(b*256 + hh*32)*736 + T0;
  const float* mk = maskbuf + wi*768;

  const bf16* ksrcA = kb + (long long)(2*wid*16 + li)*256 + lg*8;
  const bf16* ksrcB = kb + (long long)((2*wid+1)*16 + li)*256 + lg*8;
  int vrow = t256>>4, vch = t256&15;
  const bf16* vsrcA = vbT + (long long)vrow*736 + vch*8;
  const bf16* vsrcB = vbT + (long long)(vrow+16)*736 + vch*8;
  int vc_ = vch>>2, vhalf = (vch>>1)&1, vlg0 = (vch&1)*2;
  unsigned vdst0 = (unsigned)(((vc_*64 + vlg0*16     + vrow)*16 + vhalf*8) ^ (vc_<<5));
  unsigned vdst1 = (unsigned)(((vc_*64 + (vlg0+1)*16 + vrow)*16 + vhalf*8) ^ (vc_<<5));
  char* Vbase = (char*)&VlsF[sub][0];
  unsigned short* Kbase = &Kls[sub][0];

  bf16x8 qf;
  #pragma unroll
  for (int e=0;e<8;e++) qf[e]=0;
  int qrow = wid*16 + li;
  if (qrow < 49)
    qf = *(const bf16x8*)(qbuf + ((size_t)w*49+qrow)*256 + hh*32 + lg*8);

  f32x4 o0 = {0.f,0.f,0.f,0.f}, o1 = {0.f,0.f,0.f,0.f};
  float m = -3.0e38f, l = 0.f;

  {
    int j0 = t0*128;
    uint4 k0 = *(const uint4*)(ksrcA + (long long)j0*256);
    uint4 k1 = *(const uint4*)(ksrcB + (long long)j0*256);
    uint4 v0 = *(const uint4*)(vsrcA + j0);
    uint4 v1 = *(const uint4*)(vsrcB + j0);
    *(uint4*)&Kbase[2*wid*512 + lane*8]     = k0;
    *(uint4*)&Kbase[(2*wid+1)*512 + lane*8] = k1;
    *(uint2*)(Vbase + vdst0)        = make_uint2(v0.x, v0.y);
    *(uint2*)(Vbase + vdst1)        = make_uint2(v0.z, v0.w);
    *(uint2*)(Vbase + 8192 + vdst0) = make_uint2(v1.x, v1.y);
    *(uint2*)(Vbase + 8192 + vdst1) = make_uint2(v1.z, v1.w);
  }
  __syncthreads();

  for (int tile=t0; tile<t1; tile++){
    int jbase = tile*128;
    uint4 nk0, nk1, nv0, nv1;
    if (tile+1 < t1){
      int jn = jbase + 128;
      nk0 = *(const uint4*)(ksrcA + (long long)jn*256);
      nk1 = *(const uint4*)(ksrcB + (long long)jn*256);
      nv0 = *(const uint4*)(vsrcA + jn);
      nv1 = *(const uint4*)(vsrcB + jn);
    }
    __builtin_amdgcn_s_setprio(1);
    f32x4 s[8];
    #pragma unroll
    for (int t=0;t<8;t++){
      bf16x8 kf = *(const bf16x8*)&Kbase[t*512 + lane*8];
      float4 mv = *(const float4*)(mk + jbase + t*16 + lg*4);
      f32x4 cin = {mv.x, mv.y, mv.z, mv.w};
      s[t] = __builtin_amdgcn_mfma_f32_16x16x32_bf16(kf, qf, cin, 0, 0, 0);
    }
    float m0 = fmaxf(fmaxf(s[0][0], s[0][1]), fmaxf(s[0][2], s[0][3]));
    float m1 = fmaxf(fmaxf(s[1][0], s[1][1]), fmaxf(s[1][2], s[1][3]));
    float m2 = fmaxf(fmaxf(s[2][0], s[2][1]), fmaxf(s[2][2], s[2][3]));
    float m3 = fmaxf(fmaxf(s[3][0], s[3][1]), fmaxf(s[3][2], s[3][3]));
    float m4 = fmaxf(fmaxf(s[4][0], s[4][1]), fmaxf(s[4][2], s[4][3]));
    float m5 = fmaxf(fmaxf(s[5][0], s[5][1]), fmaxf(s[5][2], s[5][3]));
    float m6 = fmaxf(fmaxf(s[6][0], s[6][1]), fmaxf(s[6][2], s[6][3]));
    float m7 = fmaxf(fmaxf(s[7][0], s[7][1]), fmaxf(s[7][2], s[7][3]));
    float mt = fmaxf(fmaxf(fmaxf(m0, m1), fmaxf(m2, m3)),
                     fmaxf(fmaxf(m4, m5), fmaxf(m6, m7)));
    mt = fmaxf(mt, __shfl_xor(mt, 16));
    mt = fmaxf(mt, __shfl_xor(mt, 32));
    if (!__all(mt - m <= 8.f)){
      float mn = fmaxf(m, mt);
      float fac = fexp2(m - mn);
      m = mn;
      l *= fac;
      #pragma unroll
      for (int r=0;r<4;r++){ o0[r] *= fac; o1[r] *= fac; }
    }
    float ps = 0.f;
    #pragma unroll
    for (int t=0;t<8;t++){
      #pragma unroll
      for (int r=0;r<4;r++){
        float p = fexp2(s[t][r] - m);
        s[t][r] = p;
        ps += p;
      }
    }
    ps += __shfl_xor(ps, 16);
    ps += __shfl_xor(ps, 32);
    l += ps;
    unsigned pk[8][2];
    #pragma unroll
    for (int t=0;t<8;t++){
      pk[t][0] = cvtpk(s[t][0], s[t][1]);
      pk[t][1] = cvtpk(s[t][2], s[t][3]);
    }
    #pragma unroll
    for (int c=0;c<4;c++){
      union { unsigned u[4]; bf16x8 v; } pb;
      pb.u[0]=pk[2*c][0];   pb.u[1]=pk[2*c][1];
      pb.u[2]=pk[2*c+1][0]; pb.u[3]=pk[2*c+1][1];
      unsigned offb = (unsigned)(((c*64 + lg*16 + li)*16) ^ (c<<5));
      bf16x8 va = *(const bf16x8*)(Vbase + offb);
      bf16x8 vcf = *(const bf16x8*)(Vbase + 8192 + offb);
      o0 = __builtin_amdgcn_mfma_f32_16x16x32_bf16(va,  pb.v, o0, 0, 0, 0);
      o1 = __builtin_amdgcn_mfma_f32_16x16x32_bf16(vcf, pb.v, o1, 0, 0, 0);
    }
    __builtin_amdgcn_s_setprio(0);
    if (tile+1 < t1){
      __syncthreads();
      *(uint4*)&Kbase[2*wid*512 + lane*8]     = nk0;
      *(uint4*)&Kbase[(2*wid+1)*512 + lane*8] = nk1;
      *(uint2*)(Vbase + vdst0)        = make_uint2(nv0.x, nv0.y);
      *(uint2*)(Vbase + vdst1)        = make_uint2(nv0.z, nv0.w);
      *(uint2*)(Vbase + 8192 + vdst0) = make_uint2(nv1.x, nv1.y);
      *(uint2*)(Vbase + 8192 + vdst1) = make_uint2(nv1.z, nv1.w);
      __syncthreads();
    }
  }

  if (qrow < 49){
    float rl = 1.f / l;
    bf16* op = obuf + ((size_t)w*49 + qrow)*256 + hh*32;
    unsigned da0 = cvtpk(o0[0]*rl, o0[1]*rl);
    unsigned da1 = cvtpk(o0[2]*rl, o0[3]*rl);
    unsigned db0 = cvtpk(o1[0]*rl, o1[1]*rl);
    unsigned db1 = cvtpk(o1[2]*rl, o1[3]*rl);
    *(uint2*)(op + lg*4)      = make_uint2(da0, da1);
    *(uint2*)(op + 16 + lg*4) = make_uint2(db0, db1);
  }
}

// ---------------- K4: FUSED proj+MLP, 2-subtile 512-thread blocks (r23) -----
__global__ __launch_bounds__(512) void projmlp_kernel(
    const bf16* __restrict__ obuf, const float* __restrict__ x,
    const bf16* __restrict__ PWF, const float* __restrict__ proj_b,
    const float* __restrict__ ls1,
    const float* __restrict__ g, const float* __restrict__ bb,
    const unsigned char* __restrict__ W1F8, const float* __restrict__ fc1_b,
    const unsigned char* __restrict__ W2F8, const float* __restrict__ fc2_b,
    const float* __restrict__ ls2, float* __restrict__ out){
  __shared__ __align__(16) unsigned char xn8[2][4096];   // fp8, 2 x 4 KB
  __shared__ __align__(16) char ubuf[2][16640];          // per-sub: xo_ls | Hls8
  int tid = threadIdx.x;
  int sub = tid >> 8;
  int t256 = tid & 255;
  int wid = t256 >> 6, lane = tid & 63;
  int li = lane&15, lg = lane>>4;
  int pix0 = blockIdx.x * 32 + sub * 16;
  float* xo_ls = (float*)&ubuf[sub][0];
  unsigned char* Hls8 = (unsigned char*)&ubuf[sub][0];
  unsigned char* xn8s = &xn8[sub][0];

  // ---- Phase A: proj (bf16). A-frags + x residuals loaded up front ----
  bf16x8 a[8];
  {
    int pixA = pix0 + li;
    int b = pixA/3600, rem = pixA - b*3600;
    int gh = rem/60, gw = rem - gh*60;
    int w = b*81 + (gh/7)*9 + (gw/7);
    int t = (gh%7)*7 + (gw%7);
    long long wrow = (long long)w*49 + t;
    #pragma unroll
    for (int ks=0; ks<8; ks++)
      a[ks] = *(const bf16x8*)(obuf + wrow*256 + ks*32 + lg*8);
  }
  float pbv[4], l1v[4], l2v[4], cbv[4], xr[4][4];
  #pragma unroll
  for (int nt=0; nt<4; nt++){
    int col = wid*64 + nt*16 + li;
    pbv[nt] = proj_b[col];
    l1v[nt] = ls1[col];
    l2v[nt] = ls2[col];
    cbv[nt] = fc2_b[col];
    #pragma unroll
    for (int r=0; r<4; r++)
      xr[nt][r] = x[(size_t)(pix0 + lg*4 + r)*256 + col];  // issued early
  }
  float xov[4][4];
  #pragma unroll
  for (int nt=0; nt<4; nt++){
    const bf16* wp = PWF + (size_t)(wid*4 + nt)*4096 + lane*8;
    f32x4 z = {0.f,0.f,0.f,0.f};
    #pragma unroll
    for (int ks=0; ks<8; ks++){
      bf16x8 bfrag = *(const bf16x8*)(wp + ks*512);
      z = __builtin_amdgcn_mfma_f32_16x16x32_bf16(a[ks], bfrag, z, 0, 0, 0);
    }
    int col = wid*64 + nt*16 + li;
    #pragma unroll
    for (int r=0; r<4; r++){
      float xo = xr[nt][r] + l1v[nt]*(z[r] + pbv[nt]);
      xov[nt][r] = xo;
      xo_ls[(lg*4 + r)*260 + col] = xo;
    }
  }
  __syncthreads();
  // ---- Phase B: LN of 16 rows -> xn8 (fp8, byte swizzle ^(t&3)<<3) ----
  {
    float4 g4 = ((const float4*)g)[lane];
    float4 b4 = ((const float4*)bb)[lane];
    #pragma unroll
    for (int tt=0; tt<4; tt++){
      int t = wid*4 + tt;
      float4 v = *(const float4*)&xo_ls[t*260 + lane*4];
      float s = v.x+v.y+v.z+v.w;
      float ss = v.x*v.x+v.y*v.y+v.z*v.z+v.w*v.w;
      #pragma unroll
      for (int off=32; off; off>>=1){ s += __shfl_xor(s,off); ss += __shfl_xor(ss,off); }
      float mean = s*(1.f/256.f);
      float var = fmaxf(ss*(1.f/256.f)-mean*mean, 0.f);
      float inv = rsqrtf(var+1e-5f);
      unsigned d = 0;
      d = pk8lo((v.x-mean)*inv*g4.x+b4.x, (v.y-mean)*inv*g4.y+b4.y, d);
      d = pk8hi((v.z-mean)*inv*g4.z+b4.z, (v.w-mean)*inv*g4.w+b4.w, d);
      *(unsigned*)&xn8s[t*256 + ((lane*4) ^ ((t&3)<<3))] = d;
    }
  }
  __syncthreads();
  long a1[8];
  #pragma unroll
  for (int ks=0; ks<8; ks++)
    a1[ks] = *(const long*)&xn8s[li*256 + ks*32 + ((lg*8) ^ ((li&3)<<3))];
  // NOTE: Hls8 overwrites xo_ls from here on (xov keeps the residual in regs).
  // ---- Phase C: fp8 fc1 SWAPPED + GELU -> Hls8 (dword writes) ----
  const unsigned char* w1base = W1F8 + (size_t)(wid*16)*4096 + lane*8;
  long bcur[8], bnxt[8];
  #pragma unroll
  for (int ks=0; ks<8; ks++) bcur[ks] = *(const long*)(w1base + ks*512);
  #pragma unroll 4
  for (int nn=0; nn<16; nn++){
    if (nn < 15){
      const unsigned char* wpn = w1base + (size_t)(nn+1)*4096;
      #pragma unroll
      for (int ks=0; ks<8; ks++) bnxt[ks] = *(const long*)(wpn + ks*512);
    }
    // SWAPPED: D[row = h-col (lg*4+r) within tile][col = token li]
    f32x4 hc = {0.f,0.f,0.f,0.f};
    #pragma unroll
    for (int ks=0; ks<8; ks++)
      hc = __builtin_amdgcn_mfma_f32_16x16x32_fp8_fp8(bcur[ks], a1[ks], hc, 0, 0, 0);
    int ntg = wid*16 + nn;
    float4 bias4 = *(const float4*)&fc1_b[ntg*16 + lg*4];
    float gv[4];
    #pragma unroll
    for (int r=0; r<4; r++){
      float h = hc[r] + ((const float*)&bias4)[r];
      float z = 0.7978845608f*(h + 0.044715f*h*h*h);   // tanh-approx GELU
      z = fminf(fmaxf(z, -15.f), 15.f);
      float e = __expf(2.f*z);
      gv[r] = 0.5f*h*(1.f + (e-1.f)/(e+1.f));
    }
    unsigned d = 0;
    d = pk8lo(gv[0], gv[1], d);
    d = pk8hi(gv[2], gv[3], d);
    // H[token=li][hcols ntg*16 + lg*4 .. +3], 16B-group swizzle ntg^(li&7)
    *(unsigned*)&Hls8[li*1024 + ((ntg ^ (li&7))<<4) + lg*4] = d;
    #pragma unroll
    for (int ks=0; ks<8; ks++) bcur[ks] = bnxt[ks];
  }
  __syncthreads();
  // ---- Phase D: fp8 fc2 (h & B-frags double-buffered) + fused epilogue ----
  f32x4 oacc[4];
  #pragma unroll
  for (int nt=0; nt<4; nt++) oacc[nt] = (f32x4){0.f,0.f,0.f,0.f};
  long hcur, hnxt, b2c[4], b2n[4];
  {
    hcur = *(const long*)&Hls8[li*1024 + (((0 + (lg>>1)) ^ (li&7))<<4) + (lg&1)*8];
    #pragma unroll
    for (int nt=0; nt<4; nt++)
      b2c[nt] = *(const long*)(W2F8 + ((size_t)(wid*4+nt)*32)*512 + lane*8);
  }
  #pragma unroll 4
  for (int kc=0; kc<32; kc++){
    if (kc < 31){
      hnxt = *(const long*)&Hls8[li*1024 + (((2*(kc+1) + (lg>>1)) ^ (li&7))<<4) + (lg&1)*8];
      #pragma unroll
      for (int nt=0; nt<4; nt++)
        b2n[nt] = *(const long*)(W2F8 + ((size_t)(wid*4+nt)*32 + kc+1)*512 + lane*8);
    }
    #pragma unroll
    for (int nt=0; nt<4; nt++)
      oacc[nt] = __builtin_amdgcn_mfma_f32_16x16x32_fp8_fp8(hcur, b2c[nt], oacc[nt], 0, 0, 0);
    hcur = hnxt;
    #pragma unroll
    for (int nt=0; nt<4; nt++) b2c[nt] = b2n[nt];
  }
  #pragma unroll
  for (int nt=0; nt<4; nt++){
    int col = wid*64 + nt*16 + li;
    #pragma unroll
    for (int r=0; r<4; r++){
      size_t p = (size_t)(pix0 + lg*4 + r)*256 + col;
      out[p] = xov[nt][r] + l2v[nt]*(oacc[nt][r] + cbv[nt]);
    }
  }
}

extern "C" void kernel_launch(void* const* d_in, const int* in_sizes, int n_in,
                              void* d_out, int out_size, void* d_ws, size_t ws_size,
                              hipStream_t stream) {
  (void)in_sizes; (void)n_in; (void)out_size; (void)ws_size;
  const float* x      = (const float*)d_in[0];
  const float* y      = (const float*)d_in[1];
  const float* n1g    = (const float*)d_in[2];
  const float* n1b    = (const float*)d_in[3];
  const float* q_w    = (const float*)d_in[4];
  const float* kv_w   = (const float*)d_in[5];
  const float* proj_w = (const float*)d_in[6];
  const float* proj_b = (const float*)d_in[7];
  const float* n2g    = (const float*)d_in[8];
  const float* n2b    = (const float*)d_in[9];
  const float* fc1_w  = (const float*)d_in[10];
  const float* fc1_b  = (const float*)d_in[11];
  const float* fc2_w  = (const float*)d_in[12];
  const float* fc2_b  = (const float*)d_in[13];
  const float* ls1    = (const float*)d_in[14];
  const float* ls2    = (const float*)d_in[15];

  char* ws = (char*)d_ws;
  // Workspace (24.17 MB):
  //   qbuf  bf16[324*49*256]   @ 0          live K1..K3 (also K lo-guard: finite)
  //   kbuf  bf16[2916*256]     @ 8,128,512  live K1..K3
  //   vbufT bf16[1024*736+512] @ 9,621,504  live K1..K3 (pads zeroed by K0)
  //   obuf  bf16[324*49*256]   @ 14,745,600 live K3..K4
  //   W1F8 u8[262144] @22,874,112   W2F8 u8[262144] @23,136,256
  //   PWF bf16[65536] @23,398,400   QWF bf16[65536] @23,529,472
  //   KVF bf16[131072] @23,660,544  maskbuf f32[81*768] @23,922,688 (ends 24,171,520)
  bf16*  qbuf  = (bf16*)(ws);
  bf16*  kbuf  = (bf16*)(ws + 8128512);
  bf16*  vbufT = (bf16*)(ws + 9621504);
  bf16*  obuf  = (bf16*)(ws + 14745600);
  unsigned char* W1F8 = (unsigned char*)(ws + 22874112);
  unsigned char* W2F8 = (unsigned char*)(ws + 23136256);
  bf16*  PWF   = (bf16*)(ws + 23398400);
  bf16*  QWF   = (bf16*)(ws + 23529472);
  bf16*  KVF   = (bf16*)(ws + 23660544);
  float* maskbuf = (float*)(ws + 23922688);

  wt_kernel<<<3345, 256, 0, stream>>>(fc1_w, fc2_w, proj_w, q_w, kv_w,
                                      W1F8, W2F8, PWF, QWF, KVF, vbufT, maskbuf);
  kvq_kernel<<<1359, 256, 0, stream>>>(y, x, n1g, n1b, KVF, QWF,
                                       kbuf, vbufT, qbuf);
  attn_kernel<<<1296, 512, 0, stream>>>(qbuf, kbuf, vbufT, maskbuf, obuf);
  projmlp_kernel<<<450, 512, 0, stream>>>(obuf, x, PWF, proj_b, ls1,
                                          n2g, n2b, W1F8, fc1_b, W2F8, fc2_b, ls2,
                                          (float*)d_out);
}